// Round 22
// baseline (524.203 us; speedup 1.0000x reference)
//
#include <hip/hip_runtime.h>
#include <math.h>

// ---- problem constants ----
static constexpr int PDIM = 12800;      // 32ch*400
static constexpr int OSD  = 160;        // 10*16
static constexpr int NBLK_A = 200;      // it0 pass-A p-blocks (64 p each)

typedef _Float16 hv8  __attribute__((ext_vector_type(8)));
typedef _Float16 hv4  __attribute__((ext_vector_type(4)));
typedef _Float16 hv2  __attribute__((ext_vector_type(2)));
typedef float    f32x4 __attribute__((ext_vector_type(4)));

__device__ __forceinline__ void gload16(const void* g, void* l) {
    __builtin_amdgcn_global_load_lds(
        (const __attribute__((address_space(1))) void*)g,
        (__attribute__((address_space(3))) void*)l, 16, 0, 0);
}

__device__ __forceinline__ float hdot8(hv8 w, hv8 x) {
#if __has_builtin(__builtin_amdgcn_fdot2)
    const hv2* wp = (const hv2*)&w;
    const hv2* xp = (const hv2*)&x;
    float uh = __builtin_amdgcn_fdot2(wp[0], xp[0], 0.f, false);
    uh = __builtin_amdgcn_fdot2(wp[1], xp[1], uh, false);
    uh = __builtin_amdgcn_fdot2(wp[2], xp[2], uh, false);
    uh = __builtin_amdgcn_fdot2(wp[3], xp[3], uh, false);
    return uh;
#else
    return (float)w[0]*(float)x[0] + (float)w[1]*(float)x[1]
         + (float)w[2]*(float)x[2] + (float)w[3]*(float)x[3]
         + (float)w[4]*(float)x[4] + (float)w[5]*(float)x[5]
         + (float)w[6]*(float)x[6] + (float)w[7]*(float)x[7];
#endif
}

// ---------------- K0: prim_w[co][ci][81] -> Wk1[k][co][ci] fp16 ----------------
__global__ void k_prep_w(const float* __restrict__ w, _Float16* __restrict__ Wk1) {
    __shared__ float s[20736];          // one co-slice: [ci=256][k=81]
    int co = blockIdx.x, t = threadIdx.x;
    const float4* src = (const float4*)(w + (size_t)co*20736);
    float4* d4 = (float4*)s;
    for (int i = t; i < 5184; i += 256) d4[i] = src[i];
    __syncthreads();
    for (int k = 0; k < 81; ++k)
        Wk1[(size_t)k*65536 + co*256 + t] = (_Float16)s[t*81 + k];
}

// ---------------- K0b+K1 merged: blocks [0,16000) Wd->fp16; [16000,16512) conv1 ----------------
__global__ void k_prep_misc(const float* __restrict__ Wd, _Float16* __restrict__ Wh,
                            const float* __restrict__ x, const float* __restrict__ w,
                            const float* __restrict__ bias, _Float16* __restrict__ ht1) {
    __shared__ float sx[1296];
    __shared__ float sw[1296];
    int tid = threadIdx.x;
    if (blockIdx.x < 16000) {
        size_t i = ((size_t)blockIdx.x*256 + tid) * 4;   // 16,384,000 floats total
        float4 v = *(const float4*)(Wd + i);
        hv4 h;
        h[0] = (_Float16)v.x; h[1] = (_Float16)v.y;
        h[2] = (_Float16)v.z; h[3] = (_Float16)v.w;
        *(hv4*)(Wh + i) = h;
        return;
    }
    int bid2 = blockIdx.x - 16000;
    int b = bid2 >> 4, cog = bid2 & 15;
    for (int i = tid; i < 1296; i += 256) {
        sx[i] = x[b*1296 + i];
        sw[i] = w[cog*1296 + i];
    }
    __syncthreads();
    for (int pos = tid; pos < 784; pos += 256) {
        int y = pos / 28, xx = pos - y*28;
        float acc[16];
        #pragma unroll
        for (int c = 0; c < 16; ++c) acc[c] = 0.f;
        for (int ky = 0; ky < 9; ++ky) {
            #pragma unroll
            for (int kx = 0; kx < 9; ++kx) {
                float xv = sx[(y+ky)*36 + xx + kx];
                #pragma unroll
                for (int c = 0; c < 16; ++c)
                    acc[c] += xv * sw[c*81 + ky*9 + kx];
            }
        }
        #pragma unroll
        for (int c = 0; c < 16; ++c) {
            float r = acc[c] + bias[cog*16 + c];
            r = r > 0.f ? r : 0.f;
            ht1[((size_t)b*784 + pos)*256 + cog*16 + c] = (_Float16)r;
        }
    }
}

// ---------------- K2: primary conv as 81 shifted GEMMs, pure fp16 MFMA ----------------
// r12 structure; ksplit=5 (r16-proven: 197us, WRITE 66MB, grid 1000 = 3.9 blk/CU).
__global__ __launch_bounds__(512, 8) void k_prim_mfma(
        const _Float16* __restrict__ ht1, const _Float16* __restrict__ Wk1,
        float* __restrict__ Clin) {
    // per-buffer (halfs): A @0 (4096), B @4096; BUF=8192 (16KB)
    __shared__ _Float16 lds[16384];
    const int t   = threadIdx.x;
    const int n0  = blockIdx.x * 128;
    const int co0 = blockIdx.y * 128;
    const int z   = blockIdx.z;
    const int klo = (z*81) / 5, khi = ((z+1)*81) / 5;
    const int NSTEP = (khi - klo) * 8;

    const int srow = t >> 2, slot = t & 3;
    const int g = slot ^ ((srow >> 1) & 3);
    const size_t aSrcOff = (size_t)(co0 + srow)*256 + g*8;
    const int n1 = n0 + srow;
    const int b1 = n1/400, rr1 = n1 - b1*400, y1 = rr1/20, x1 = rr1 - y1*20;
    const size_t bOff1 = ((size_t)b1*784 + y1*28 + x1)*256 + g*8;

    const int l = t & 63, w8 = t >> 6;
    const int wm = w8 >> 2, wn = w8 & 3;
    const int lm = l & 15, lk = l >> 4;
    int aoff[4], boff[2];
    #pragma unroll
    for (int i = 0; i < 4; ++i) {
        int ra = wm*64 + i*16 + lm;
        aoff[i] = ra*32 + ((lk ^ ((ra>>1)&3))*8);
    }
    #pragma unroll
    for (int j = 0; j < 2; ++j) {
        int rb = wn*32 + j*16 + lm;
        boff[j] = 4096 + rb*32 + ((lk ^ ((rb>>1)&3))*8);
    }

    f32x4 acc[4][2];
    #pragma unroll
    for (int i = 0; i < 4; ++i)
        #pragma unroll
        for (int j = 0; j < 2; ++j) { acc[i][j][0]=0.f; acc[i][j][1]=0.f; acc[i][j][2]=0.f; acc[i][j][3]=0.f; }

#define STAGE(S, LB) { int k_ = klo + ((S) >> 3), c_ = (S) & 7; \
        size_t ao = (size_t)k_*65536 + c_*32 + aSrcOff; \
        gload16(Wk1 + ao, (LB) + t*8); \
        int spk_ = (k_/9)*28 + (k_ - (k_/9)*9); \
        size_t so = (size_t)spk_*256 + c_*32; \
        gload16(ht1 + bOff1 + so, (LB) + 4096 + t*8); }

#define COMPUTE(L) { hv8 a1[4]; \
        _Pragma("unroll") for (int mi = 0; mi < 4; ++mi) \
            a1[mi] = *(const hv8*)((L) + aoff[mi]); \
        _Pragma("unroll") for (int nj = 0; nj < 2; ++nj) { \
            hv8 q1 = *(const hv8*)((L) + boff[nj]); \
            _Pragma("unroll") for (int mi = 0; mi < 4; ++mi) \
                acc[mi][nj] = __builtin_amdgcn_mfma_f32_16x16x32_f16(a1[mi], q1, acc[mi][nj], 0, 0, 0); } }

    STAGE(0, lds);
    __syncthreads();

    for (int s = 0; s < NSTEP; ++s) {
        const int d = s & 1;
        _Float16* Lnext = lds + (d ? 0 : 8192);
        const _Float16* L = lds + (d ? 8192 : 0);
        if ((s + 1) < NSTEP) STAGE(s+1, Lnext);
        COMPUTE(L);
        __syncthreads();
    }

    #pragma unroll
    for (int mi = 0; mi < 4; ++mi) {
        #pragma unroll
        for (int nj = 0; nj < 2; ++nj) {
            int nn = n0 + wn*32 + nj*16 + lm;
            #pragma unroll
            for (int r = 0; r < 4; ++r) {
                int co = co0 + wm*64 + mi*16 + lk*4 + r;
                atomicAdd(&Clin[(size_t)co*12800 + nn], acc[mi][nj][r]);
            }
        }
    }
#undef STAGE
#undef COMPUTE
}

// ---------------- K2b: squared-norm partials per (b,u) from Clin+bias ----------------
__global__ void k_ssq(const float* __restrict__ Clin, const float* __restrict__ bias,
                      float* __restrict__ ssq) {
    __shared__ float r0[256], r1[256];
    int tid = threadIdx.x;
    int e = blockIdx.x*256 + tid;
    int co = e / 12800;
    int unit = co >> 5;
    float val = Clin[e] + bias[co];
    int n0b = (blockIdx.x % 50) * 256;
    int bn0 = n0b / 400;
    int nb  = (bn0+1)*400 - n0b;
    float v2 = val * val;
    bool hi = (tid >= nb);
    r0[tid] = hi ? 0.f : v2;
    r1[tid] = hi ? v2 : 0.f;
    __syncthreads();
    for (int st = 128; st > 0; st >>= 1) {
        if (tid < st) { r0[tid] += r0[tid+st]; r1[tid] += r1[tid+st]; }
        __syncthreads();
    }
    if (tid == 0) {
        atomicAdd(&ssq[bn0*8 + unit], r0[0]);
        if (nb < 256) atomicAdd(&ssq[(bn0+1)*8 + unit], r1[0]);
    }
}

// ---------------- K3: xq[p][b*8+u] = fp16((Clin[co][n]+bias)*scl(b,u)) ----------------
__global__ void k_xq2(const float* __restrict__ Clin, const float* __restrict__ bias,
                      const float* __restrict__ ssq, _Float16* __restrict__ xq) {
    __shared__ float sT[32][257];
    __shared__ float sS[256];
    int p0 = blockIdx.x*32, tid = threadIdx.x;
    {
        float q = ssq[tid];
        sS[tid] = sqrtf(q) / (1.f + q);
    }
    __syncthreads();
    for (int r = 0; r < 32; ++r) {
        int e = r*256 + tid;
        int bu = e >> 5, pi = e & 31;
        int p = p0 + pi;
        int ch = p / 400, rr = p - ch*400;
        int unit = bu & 7, bn = bu >> 3;
        int co = unit*32 + ch;
        sT[pi][bu] = (Clin[(size_t)co*12800 + bn*400 + rr] + bias[co]) * sS[bu];
    }
    __syncthreads();
    for (int r = 0; r < 32; ++r)
        xq[(size_t)(p0+r)*256 + tid] = (_Float16)sT[r][tid];
}

// ---------------- K5: it0 pass A as MFMA GEMM (r18-proven) ----------------
__global__ __launch_bounds__(256) void k_sj0_mfma(const _Float16* __restrict__ Wh,
        const _Float16* __restrict__ xq, float* __restrict__ sjp,
        float* __restrict__ cdenAB) {
    __shared__ float lsj[4*5120];       // 80KB: one copy per wave
    int tid = threadIdx.x;
    if (blockIdx.x == 0 && tid < 32) cdenAB[tid] = 0.f;
    const int w = tid >> 6, l = tid & 63;
    const int col = l & 15, pg = l >> 4;
    const int p0 = blockIdx.x * 64;

    f32x4 acc[2][10];
    #pragma unroll
    for (int mi = 0; mi < 2; ++mi)
        #pragma unroll
        for (int nj = 0; nj < 10; ++nj) { acc[mi][nj][0]=0.f; acc[mi][nj][1]=0.f; acc[mi][nj][2]=0.f; acc[mi][nj][3]=0.f; }

    for (int s = 0; s < 4; ++s) {
        int pp = p0 + (w*4 + s)*4 + pg;
        hv8 a0 = *(const hv8*)(xq + (size_t)pp*256 + col*8);
        hv8 a1 = *(const hv8*)(xq + (size_t)pp*256 + (16 + col)*8);
        const hv8* wb = (const hv8*)(Wh + (size_t)pp*1280);
        #pragma unroll
        for (int nj = 0; nj < 10; ++nj) {
            hv8 bf = wb[nj*16 + col];
            acc[0][nj] = __builtin_amdgcn_mfma_f32_16x16x32_f16(a0, bf, acc[0][nj], 0, 0, 0);
            acc[1][nj] = __builtin_amdgcn_mfma_f32_16x16x32_f16(a1, bf, acc[1][nj], 0, 0, 0);
        }
    }

    float* my = lsj + w*5120;
    #pragma unroll
    for (int mi = 0; mi < 2; ++mi)
        #pragma unroll
        for (int nj = 0; nj < 10; ++nj)
            #pragma unroll
            for (int r = 0; r < 4; ++r) {
                int b = mi*16 + pg*4 + r;
                int os = nj*16 + col;
                my[b*160 + os] = acc[mi][nj][r];
            }
    __syncthreads();
    const float uc = 1.f / 12800.f;
    float* outp = sjp + (size_t)blockIdx.x*5120;
    for (int e = tid; e < 5120; e += 256)
        outp[e] = (lsj[e] + lsj[5120+e] + lsj[10240+e] + lsj[15360+e]) * uc;
}

// ---------------- K6: reduce np partials -> s_j (/cden if useDen) -> squash over O -> v ----------------
__global__ void k_reduce_squash(const float* __restrict__ sjp, float* __restrict__ v,
                                const float* __restrict__ cden, int useDen, int np,
                                float* __restrict__ dout, int writeOut) {
    __shared__ float ps[640];
    __shared__ float sc[16];
    int tid = threadIdx.x;
    int b = blockIdx.x;
    int q = tid / 160, el = tid - q*160;
    float s = 0.f;
    for (int k = q; k < np; k += 4) s += sjp[(size_t)k*5120 + b*160 + el];
    ps[tid] = s;
    __syncthreads();
    if (tid < 160) {
        float sfull = ps[tid] + ps[160+tid] + ps[320+tid] + ps[480+tid];
        if (useDen) sfull *= 1.f / cden[tid >> 4];
        ps[tid] = sfull;
    }
    __syncthreads();
    if (tid < 16) {
        float msq = 0.f;
        #pragma unroll
        for (int o = 0; o < 10; ++o) { float t_ = ps[o*16 + tid]; msq += t_*t_; }
        sc[tid] = sqrtf(msq) / (1.f + msq);
    }
    __syncthreads();
    if (tid < 160) {
        float val = ps[tid] * sc[tid & 15];
        int e = b*160 + tid;
        v[e] = val;
        if (writeOut) dout[e] = val;
    }
}

// ---------------- K7: fused pass B + next pass A; 640 thr, fp16 sxq, padded sv2, fdot2 ----------------
// phase 1: two thread-halves each cover 16 bq for thread (pl,o); LDS pair-reduce; e=exp->se.
// phase 2: wave w (of 10) owns os-tile nj=w, all 32 p (8 K-steps), disjoint sjp stores.
// sv2[o*516 + b*16 + s]: o-stride 516 f -> banks 4 apart (<=2-way, free) vs 5-way before.
__global__ __launch_bounds__(640) void k_fused_bs(const _Float16* __restrict__ Wh,
        const _Float16* __restrict__ xqh, const float* __restrict__ v,
        float* __restrict__ bij, float* __restrict__ cden, float* __restrict__ sjp) {
    __shared__ float sv2[10*516];       // 20640B, padded [o][b][s]
    __shared__ _Float16 sxq[32*264];    // 16896B, fp16 [pl][bu]
    __shared__ float se[320];
    __shared__ float ph[640];
    int tid = threadIdx.x;
    int p0 = blockIdx.x*32;
    for (int e = tid; e < 5120; e += 640) {
        int b = e / 160, rem = e - b*160;
        int o = rem >> 4, s = rem & 15;
        sv2[o*516 + b*16 + s] = v[e];
    }
    for (int e = tid; e < 1024; e += 640) {
        int pl = e >> 5, grp = e & 31;
        *(hv8*)&sxq[pl*264 + grp*8] = *(const hv8*)(xqh + (size_t)(p0+pl)*256 + grp*8);
    }
    __syncthreads();
    // ---- phase 1: agree partials, each half covers 16 bq ----
    {
        int h = (tid >= 320) ? 1 : 0;
        int base = tid - h*320;
        int pl = base / 10, o = base - pl*10;
        int p = p0 + pl;
        const hv8* wr = (const hv8*)(Wh + (size_t)p*1280 + o*128);
        float acc = 0.f;
        int bq0 = h*16;
        #pragma unroll
        for (int hf = 0; hf < 2; ++hf) {
            hv8 wreg[8];
            #pragma unroll
            for (int i = 0; i < 8; ++i) wreg[i] = wr[hf*8 + i];
            for (int bq = bq0; bq < bq0+16; ++bq) {
                hv8 xv = *(const hv8*)&sxq[pl*264 + bq*8];
                #pragma unroll
                for (int sg = 0; sg < 2; ++sg) {
                    float4 vs = *(const float4*)&sv2[o*516 + bq*16 + hf*8 + sg*4];
                    float vsv[4] = {vs.x, vs.y, vs.z, vs.w};
                    #pragma unroll
                    for (int s4 = 0; s4 < 4; ++s4) {
                        float uh = hdot8(wreg[sg*4 + s4], xv);
                        acc += uh * vsv[s4];
                    }
                }
            }
        }
        ph[tid] = acc;
    }
    __syncthreads();
    if (tid < 320) {
        int pl = tid / 10, o = tid - pl*10;
        float acc = ph[tid] + ph[tid + 320];
        float bn_ = bij[(p0+pl)*10 + o] + acc * (1.f/32.f);
        bij[(p0+pl)*10 + o] = bn_;
        se[tid] = __expf(bn_);      // se[pl*10 + o]
    }
    __syncthreads();
    if (tid < 10) {
        float s_ = 0.f;
        #pragma unroll
        for (int j = 0; j < 32; ++j) s_ += se[tid + j*10];
        atomicAdd(&cden[tid], s_);
    }
    // ---- phase 2: wave w owns os-tile nj=w; all 32 p; direct disjoint stores ----
    {
        int w = tid >> 6, l = tid & 63;
        const int col = l & 15, pg = l >> 4;
        f32x4 acc2[2];
        acc2[0][0]=0.f; acc2[0][1]=0.f; acc2[0][2]=0.f; acc2[0][3]=0.f;
        acc2[1][0]=0.f; acc2[1][1]=0.f; acc2[1][2]=0.f; acc2[1][3]=0.f;
        for (int s2 = 0; s2 < 8; ++s2) {
            int plocal = s2*4 + pg;
            int pp = p0 + plocal;
            hv8 a0 = *(const hv8*)(xqh + (size_t)pp*256 + col*8);
            hv8 a1 = *(const hv8*)(xqh + (size_t)pp*256 + (16 + col)*8);
            const hv8* wb = (const hv8*)(Wh + (size_t)pp*1280);
            _Float16 eh = (_Float16)se[plocal*10 + w];
            hv8 bf = wb[w*16 + col];
            #pragma unroll
            for (int j = 0; j < 8; ++j) bf[j] *= eh;
            acc2[0] = __builtin_amdgcn_mfma_f32_16x16x32_f16(a0, bf, acc2[0], 0, 0, 0);
            acc2[1] = __builtin_amdgcn_mfma_f32_16x16x32_f16(a1, bf, acc2[1], 0, 0, 0);
        }
        float* outp = sjp + (size_t)blockIdx.x*5120;
        #pragma unroll
        for (int mi = 0; mi < 2; ++mi)
            #pragma unroll
            for (int r = 0; r < 4; ++r) {
                int b = mi*16 + pg*4 + r;
                int os = w*16 + col;
                outp[b*160 + os] = acc2[mi][r];
            }
    }
}

extern "C" void kernel_launch(void* const* d_in, const int* in_sizes, int n_in,
                              void* d_out, int out_size, void* d_ws, size_t ws_size,
                              hipStream_t stream) {
    const float* x   = (const float*)d_in[0];
    const float* c1w = (const float*)d_in[1];
    const float* c1b = (const float*)d_in[2];
    const float* pw  = (const float*)d_in[3];
    const float* pb  = (const float*)d_in[4];
    const float* Wd  = (const float*)d_in[5];
    float* out = (float*)d_out;

    // workspace map (bytes); total 69,870,656 == proven footprint
    char* wsb = (char*)d_ws;
    _Float16* ht1 = (_Float16*)(wsb);                 // 12,845,056
    _Float16* Wk1 = (_Float16*)(wsb + 12845056);      // 10,616,832
    float* Clin = (float*)(wsb + 23461888);           // 13,107,200
    char* tailb = wsb + 36569088;
    float* bij   = (float*)tailb;                     // 128,000 f -> ends 37,081,088
    float* ssq   = bij + 128000;                      // 256 f     -> ends 37,082,112
    float* vv    = ssq + 256;                         // 5,120 f   -> ends 37,102,592
    _Float16* Wh = (_Float16*)(wsb + 37102656);       // 32,768,000 B -> ends 69,870,656
    // aliases:
    float* cdenA = ssq;                      // ssq dead after k_xq2; zeroed in k_sj0_mfma
    float* cdenB = ssq + 16;
    _Float16* xq = (_Float16*)(wsb);         // 6.55MB over ht1 (dead after GEMM)
    float* sjp = (float*)(wsb + 23461888);   // over Clin (dead after xq2); 400*5120 f = 8.2MB

    hipMemsetAsync(Clin, 0, 13107200, stream);
    hipMemsetAsync(bij, 0, (128000 + 256)*sizeof(float), stream);  // bij + ssq

    k_prep_misc<<<16512, 256, 0, stream>>>(Wd, Wh, x, c1w, c1b, ht1);
    k_prep_w<<<256, 256, 0, stream>>>(pw, Wk1);
    k_prim_mfma<<<dim3(100,2,5), 512, 0, stream>>>(ht1, Wk1, Clin);
    k_ssq<<<12800, 256, 0, stream>>>(Clin, pb, ssq);
    k_xq2<<<400, 256, 0, stream>>>(Clin, pb, ssq, xq);

    // it0: uniform coupling as MFMA GEMM (also zeroes cdenA/cdenB)
    k_sj0_mfma<<<NBLK_A, 256, 0, stream>>>(Wh, xq, sjp, cdenA);
    k_reduce_squash<<<32, 640, 0, stream>>>(sjp, vv, cdenA, 0, NBLK_A, out, 0);
    // it1: fused bij-update + MFMA s~ (normalize-after-sum)
    k_fused_bs<<<400, 640, 0, stream>>>(Wh, xq, vv, bij, cdenA, sjp);
    k_reduce_squash<<<32, 640, 0, stream>>>(sjp, vv, cdenA, 1, 400, out, 0);
    // it2
    k_fused_bs<<<400, 640, 0, stream>>>(Wh, xq, vv, bij, cdenB, sjp);
    k_reduce_squash<<<32, 640, 0, stream>>>(sjp, vv, cdenB, 1, 400, out, 1);
}

// Round 23
// 510.861 us; speedup vs baseline: 1.0261x; 1.0261x over previous
//
#include <hip/hip_runtime.h>
#include <math.h>

// ---- problem constants ----
static constexpr int PDIM = 12800;      // 32ch*400
static constexpr int OSD  = 160;        // 10*16
static constexpr int NBLK_A = 200;      // it0 pass-A p-blocks (64 p each)

typedef _Float16 hv8  __attribute__((ext_vector_type(8)));
typedef _Float16 hv4  __attribute__((ext_vector_type(4)));
typedef float    f32x4 __attribute__((ext_vector_type(4)));

__device__ __forceinline__ void gload16(const void* g, void* l) {
    __builtin_amdgcn_global_load_lds(
        (const __attribute__((address_space(1))) void*)g,
        (__attribute__((address_space(3))) void*)l, 16, 0, 0);
}

// ---------------- K0: prim_w[co][ci][81] -> Wk1[k][co][ci] fp16 ----------------
__global__ void k_prep_w(const float* __restrict__ w, _Float16* __restrict__ Wk1) {
    __shared__ float s[20736];          // one co-slice: [ci=256][k=81]
    int co = blockIdx.x, t = threadIdx.x;
    const float4* src = (const float4*)(w + (size_t)co*20736);
    float4* d4 = (float4*)s;
    for (int i = t; i < 5184; i += 256) d4[i] = src[i];
    __syncthreads();
    for (int k = 0; k < 81; ++k)
        Wk1[(size_t)k*65536 + co*256 + t] = (_Float16)s[t*81 + k];
}

// ---------------- K0b+K1 merged: blocks [0,16000) Wd->fp16; [16000,16512) conv1 ----------------
__global__ void k_prep_misc(const float* __restrict__ Wd, _Float16* __restrict__ Wh,
                            const float* __restrict__ x, const float* __restrict__ w,
                            const float* __restrict__ bias, _Float16* __restrict__ ht1) {
    __shared__ float sx[1296];
    __shared__ float sw[1296];
    int tid = threadIdx.x;
    if (blockIdx.x < 16000) {
        size_t i = ((size_t)blockIdx.x*256 + tid) * 4;   // 16,384,000 floats total
        float4 v = *(const float4*)(Wd + i);
        hv4 h;
        h[0] = (_Float16)v.x; h[1] = (_Float16)v.y;
        h[2] = (_Float16)v.z; h[3] = (_Float16)v.w;
        *(hv4*)(Wh + i) = h;
        return;
    }
    int bid2 = blockIdx.x - 16000;
    int b = bid2 >> 4, cog = bid2 & 15;
    for (int i = tid; i < 1296; i += 256) {
        sx[i] = x[b*1296 + i];
        sw[i] = w[cog*1296 + i];
    }
    __syncthreads();
    for (int pos = tid; pos < 784; pos += 256) {
        int y = pos / 28, xx = pos - y*28;
        float acc[16];
        #pragma unroll
        for (int c = 0; c < 16; ++c) acc[c] = 0.f;
        for (int ky = 0; ky < 9; ++ky) {
            #pragma unroll
            for (int kx = 0; kx < 9; ++kx) {
                float xv = sx[(y+ky)*36 + xx + kx];
                #pragma unroll
                for (int c = 0; c < 16; ++c)
                    acc[c] += xv * sw[c*81 + ky*9 + kx];
            }
        }
        #pragma unroll
        for (int c = 0; c < 16; ++c) {
            float r = acc[c] + bias[cog*16 + c];
            r = r > 0.f ? r : 0.f;
            ht1[((size_t)b*784 + pos)*256 + cog*16 + c] = (_Float16)r;
        }
    }
}

// ---------------- K2: primary conv as 81 shifted GEMMs, pure fp16 MFMA ----------------
// r12 structure; ksplit=5 (r16-proven: 197us, WRITE 66MB, grid 1000 = 3.9 blk/CU).
__global__ __launch_bounds__(512, 8) void k_prim_mfma(
        const _Float16* __restrict__ ht1, const _Float16* __restrict__ Wk1,
        float* __restrict__ Clin) {
    // per-buffer (halfs): A @0 (4096), B @4096; BUF=8192 (16KB)
    __shared__ _Float16 lds[16384];
    const int t   = threadIdx.x;
    const int n0  = blockIdx.x * 128;
    const int co0 = blockIdx.y * 128;
    const int z   = blockIdx.z;
    const int klo = (z*81) / 5, khi = ((z+1)*81) / 5;
    const int NSTEP = (khi - klo) * 8;

    const int srow = t >> 2, slot = t & 3;
    const int g = slot ^ ((srow >> 1) & 3);
    const size_t aSrcOff = (size_t)(co0 + srow)*256 + g*8;
    const int n1 = n0 + srow;
    const int b1 = n1/400, rr1 = n1 - b1*400, y1 = rr1/20, x1 = rr1 - y1*20;
    const size_t bOff1 = ((size_t)b1*784 + y1*28 + x1)*256 + g*8;

    const int l = t & 63, w8 = t >> 6;
    const int wm = w8 >> 2, wn = w8 & 3;
    const int lm = l & 15, lk = l >> 4;
    int aoff[4], boff[2];
    #pragma unroll
    for (int i = 0; i < 4; ++i) {
        int ra = wm*64 + i*16 + lm;
        aoff[i] = ra*32 + ((lk ^ ((ra>>1)&3))*8);
    }
    #pragma unroll
    for (int j = 0; j < 2; ++j) {
        int rb = wn*32 + j*16 + lm;
        boff[j] = 4096 + rb*32 + ((lk ^ ((rb>>1)&3))*8);
    }

    f32x4 acc[4][2];
    #pragma unroll
    for (int i = 0; i < 4; ++i)
        #pragma unroll
        for (int j = 0; j < 2; ++j) { acc[i][j][0]=0.f; acc[i][j][1]=0.f; acc[i][j][2]=0.f; acc[i][j][3]=0.f; }

#define STAGE(S, LB) { int k_ = klo + ((S) >> 3), c_ = (S) & 7; \
        size_t ao = (size_t)k_*65536 + c_*32 + aSrcOff; \
        gload16(Wk1 + ao, (LB) + t*8); \
        int spk_ = (k_/9)*28 + (k_ - (k_/9)*9); \
        size_t so = (size_t)spk_*256 + c_*32; \
        gload16(ht1 + bOff1 + so, (LB) + 4096 + t*8); }

#define COMPUTE(L) { hv8 a1[4]; \
        _Pragma("unroll") for (int mi = 0; mi < 4; ++mi) \
            a1[mi] = *(const hv8*)((L) + aoff[mi]); \
        _Pragma("unroll") for (int nj = 0; nj < 2; ++nj) { \
            hv8 q1 = *(const hv8*)((L) + boff[nj]); \
            _Pragma("unroll") for (int mi = 0; mi < 4; ++mi) \
                acc[mi][nj] = __builtin_amdgcn_mfma_f32_16x16x32_f16(a1[mi], q1, acc[mi][nj], 0, 0, 0); } }

    STAGE(0, lds);
    __syncthreads();

    for (int s = 0; s < NSTEP; ++s) {
        const int d = s & 1;
        _Float16* Lnext = lds + (d ? 0 : 8192);
        const _Float16* L = lds + (d ? 8192 : 0);
        if ((s + 1) < NSTEP) STAGE(s+1, Lnext);
        COMPUTE(L);
        __syncthreads();
    }

    #pragma unroll
    for (int mi = 0; mi < 4; ++mi) {
        #pragma unroll
        for (int nj = 0; nj < 2; ++nj) {
            int nn = n0 + wn*32 + nj*16 + lm;
            #pragma unroll
            for (int r = 0; r < 4; ++r) {
                int co = co0 + wm*64 + mi*16 + lk*4 + r;
                atomicAdd(&Clin[(size_t)co*12800 + nn], acc[mi][nj][r]);
            }
        }
    }
#undef STAGE
#undef COMPUTE
}

// ---------------- K2b: squared-norm partials per (b,u) from Clin+bias ----------------
__global__ void k_ssq(const float* __restrict__ Clin, const float* __restrict__ bias,
                      float* __restrict__ ssq) {
    __shared__ float r0[256], r1[256];
    int tid = threadIdx.x;
    int e = blockIdx.x*256 + tid;
    int co = e / 12800;
    int unit = co >> 5;
    float val = Clin[e] + bias[co];
    int n0b = (blockIdx.x % 50) * 256;
    int bn0 = n0b / 400;
    int nb  = (bn0+1)*400 - n0b;
    float v2 = val * val;
    bool hi = (tid >= nb);
    r0[tid] = hi ? 0.f : v2;
    r1[tid] = hi ? v2 : 0.f;
    __syncthreads();
    for (int st = 128; st > 0; st >>= 1) {
        if (tid < st) { r0[tid] += r0[tid+st]; r1[tid] += r1[tid+st]; }
        __syncthreads();
    }
    if (tid == 0) {
        atomicAdd(&ssq[bn0*8 + unit], r0[0]);
        if (nb < 256) atomicAdd(&ssq[(bn0+1)*8 + unit], r1[0]);
    }
}

// ---------------- K3: xq[p][b*8+u] = fp16((Clin[co][n]+bias)*scl(b,u)) ----------------
__global__ void k_xq2(const float* __restrict__ Clin, const float* __restrict__ bias,
                      const float* __restrict__ ssq, _Float16* __restrict__ xq) {
    __shared__ float sT[32][257];
    __shared__ float sS[256];
    int p0 = blockIdx.x*32, tid = threadIdx.x;
    {
        float q = ssq[tid];
        sS[tid] = sqrtf(q) / (1.f + q);
    }
    __syncthreads();
    for (int r = 0; r < 32; ++r) {
        int e = r*256 + tid;
        int bu = e >> 5, pi = e & 31;
        int p = p0 + pi;
        int ch = p / 400, rr = p - ch*400;
        int unit = bu & 7, bn = bu >> 3;
        int co = unit*32 + ch;
        sT[pi][bu] = (Clin[(size_t)co*12800 + bn*400 + rr] + bias[co]) * sS[bu];
    }
    __syncthreads();
    for (int r = 0; r < 32; ++r)
        xq[(size_t)(p0+r)*256 + tid] = (_Float16)sT[r][tid];
}

// ---------------- K5: it0 pass A as MFMA GEMM (r18-proven) ----------------
__global__ __launch_bounds__(256) void k_sj0_mfma(const _Float16* __restrict__ Wh,
        const _Float16* __restrict__ xq, float* __restrict__ sjp,
        float* __restrict__ cdenAB) {
    __shared__ float lsj[4*5120];       // 80KB: one copy per wave
    int tid = threadIdx.x;
    if (blockIdx.x == 0 && tid < 32) cdenAB[tid] = 0.f;
    const int w = tid >> 6, l = tid & 63;
    const int col = l & 15, pg = l >> 4;
    const int p0 = blockIdx.x * 64;

    f32x4 acc[2][10];
    #pragma unroll
    for (int mi = 0; mi < 2; ++mi)
        #pragma unroll
        for (int nj = 0; nj < 10; ++nj) { acc[mi][nj][0]=0.f; acc[mi][nj][1]=0.f; acc[mi][nj][2]=0.f; acc[mi][nj][3]=0.f; }

    for (int s = 0; s < 4; ++s) {
        int pp = p0 + (w*4 + s)*4 + pg;
        hv8 a0 = *(const hv8*)(xq + (size_t)pp*256 + col*8);
        hv8 a1 = *(const hv8*)(xq + (size_t)pp*256 + (16 + col)*8);
        const hv8* wb = (const hv8*)(Wh + (size_t)pp*1280);
        #pragma unroll
        for (int nj = 0; nj < 10; ++nj) {
            hv8 bf = wb[nj*16 + col];
            acc[0][nj] = __builtin_amdgcn_mfma_f32_16x16x32_f16(a0, bf, acc[0][nj], 0, 0, 0);
            acc[1][nj] = __builtin_amdgcn_mfma_f32_16x16x32_f16(a1, bf, acc[1][nj], 0, 0, 0);
        }
    }

    float* my = lsj + w*5120;
    #pragma unroll
    for (int mi = 0; mi < 2; ++mi)
        #pragma unroll
        for (int nj = 0; nj < 10; ++nj)
            #pragma unroll
            for (int r = 0; r < 4; ++r) {
                int b = mi*16 + pg*4 + r;
                int os = nj*16 + col;
                my[b*160 + os] = acc[mi][nj][r];
            }
    __syncthreads();
    const float uc = 1.f / 12800.f;
    float* outp = sjp + (size_t)blockIdx.x*5120;
    for (int e = tid; e < 5120; e += 256)
        outp[e] = (lsj[e] + lsj[5120+e] + lsj[10240+e] + lsj[15360+e]) * uc;
}

// ---------------- K6: reduce np partials -> s_j (/cden if useDen) -> squash over O -> v ----------------
__global__ void k_reduce_squash(const float* __restrict__ sjp, float* __restrict__ v,
                                const float* __restrict__ cden, int useDen, int np,
                                float* __restrict__ dout, int writeOut) {
    __shared__ float ps[640];
    __shared__ float sc[16];
    int tid = threadIdx.x;
    int b = blockIdx.x;
    int q = tid / 160, el = tid - q*160;
    float s = 0.f;
    for (int k = q; k < np; k += 4) s += sjp[(size_t)k*5120 + b*160 + el];
    ps[tid] = s;
    __syncthreads();
    if (tid < 160) {
        float sfull = ps[tid] + ps[160+tid] + ps[320+tid] + ps[480+tid];
        if (useDen) sfull *= 1.f / cden[tid >> 4];
        ps[tid] = sfull;
    }
    __syncthreads();
    if (tid < 16) {
        float msq = 0.f;
        #pragma unroll
        for (int o = 0; o < 10; ++o) { float t_ = ps[o*16 + tid]; msq += t_*t_; }
        sc[tid] = sqrtf(msq) / (1.f + msq);
    }
    __syncthreads();
    if (tid < 160) {
        float val = ps[tid] * sc[tid & 15];
        int e = b*160 + tid;
        v[e] = val;
        if (writeOut) dout[e] = val;
    }
}

// ---------------- K7: fused pass B + next pass A; 640 thr (10 waves) — r21-proven ----------------
// phase 1: two thread-halves each cover 16 bq for thread (pl,o); LDS pair-reduce; e=exp->se.
// phase 2: wave w (of 10) owns os-tile nj=w, all 32 p (8 K-steps), disjoint sjp stores.
__global__ __launch_bounds__(640) void k_fused_bs(const _Float16* __restrict__ Wh,
        const _Float16* __restrict__ xqh, const float* __restrict__ v,
        float* __restrict__ bij, float* __restrict__ cden, float* __restrict__ sjp) {
    __shared__ float sv[5120];
    __shared__ float sxq[32*260];
    __shared__ float se[320];
    __shared__ float ph[640];
    int tid = threadIdx.x;
    int p0 = blockIdx.x*32;
    for (int e = tid; e < 5120; e += 640) sv[e] = v[e];
    for (int e = tid; e < 1024; e += 640) {
        int pl = e >> 5, grp = e & 31;
        hv8 xv = *(const hv8*)(xqh + (size_t)(p0+pl)*256 + grp*8);
        #pragma unroll
        for (int j = 0; j < 8; ++j) sxq[pl*260 + grp*8 + j] = (float)xv[j];
    }
    __syncthreads();
    // ---- phase 1: agree partials, each half covers 16 bq ----
    {
        int h = (tid >= 320) ? 1 : 0;
        int base = tid - h*320;
        int pl = base / 10, o = base - pl*10;
        int p = p0 + pl;
        const hv8* wr = (const hv8*)(Wh + (size_t)p*1280 + o*128);
        float acc = 0.f;
        int bq0 = h*16;
        #pragma unroll
        for (int hf = 0; hf < 2; ++hf) {
            hv8 wreg[8];
            #pragma unroll
            for (int i = 0; i < 8; ++i) wreg[i] = wr[hf*8 + i];
            for (int bq = bq0; bq < bq0+16; ++bq) {
                float4 x0 = *(const float4*)&sxq[pl*260 + bq*8];
                float4 x1 = *(const float4*)&sxq[pl*260 + bq*8 + 4];
                #pragma unroll
                for (int sg = 0; sg < 2; ++sg) {
                    float4 vs = *(const float4*)&sv[bq*160 + o*16 + hf*8 + sg*4];
                    float vsv[4] = {vs.x, vs.y, vs.z, vs.w};
                    #pragma unroll
                    for (int s4 = 0; s4 < 4; ++s4) {
                        hv8 wv = wreg[sg*4 + s4];
                        float uh = (float)wv[0]*x0.x + (float)wv[1]*x0.y + (float)wv[2]*x0.z + (float)wv[3]*x0.w
                                 + (float)wv[4]*x1.x + (float)wv[5]*x1.y + (float)wv[6]*x1.z + (float)wv[7]*x1.w;
                        acc += uh * vsv[s4];
                    }
                }
            }
        }
        ph[tid] = acc;
    }
    __syncthreads();
    if (tid < 320) {
        int pl = tid / 10, o = tid - pl*10;
        float acc = ph[tid] + ph[tid + 320];
        float bn_ = bij[(p0+pl)*10 + o] + acc * (1.f/32.f);
        bij[(p0+pl)*10 + o] = bn_;
        se[tid] = __expf(bn_);      // se[pl*10 + o]
    }
    __syncthreads();
    if (tid < 10) {
        float s_ = 0.f;
        #pragma unroll
        for (int j = 0; j < 32; ++j) s_ += se[tid + j*10];
        atomicAdd(&cden[tid], s_);
    }
    // ---- phase 2: wave w owns os-tile nj=w; all 32 p; direct disjoint stores ----
    {
        int w = tid >> 6, l = tid & 63;
        const int col = l & 15, pg = l >> 4;
        f32x4 acc2[2];
        acc2[0][0]=0.f; acc2[0][1]=0.f; acc2[0][2]=0.f; acc2[0][3]=0.f;
        acc2[1][0]=0.f; acc2[1][1]=0.f; acc2[1][2]=0.f; acc2[1][3]=0.f;
        for (int s2 = 0; s2 < 8; ++s2) {
            int plocal = s2*4 + pg;
            int pp = p0 + plocal;
            hv8 a0 = *(const hv8*)(xqh + (size_t)pp*256 + col*8);
            hv8 a1 = *(const hv8*)(xqh + (size_t)pp*256 + (16 + col)*8);
            const hv8* wb = (const hv8*)(Wh + (size_t)pp*1280);
            _Float16 eh = (_Float16)se[plocal*10 + w];
            hv8 bf = wb[w*16 + col];
            #pragma unroll
            for (int j = 0; j < 8; ++j) bf[j] *= eh;
            acc2[0] = __builtin_amdgcn_mfma_f32_16x16x32_f16(a0, bf, acc2[0], 0, 0, 0);
            acc2[1] = __builtin_amdgcn_mfma_f32_16x16x32_f16(a1, bf, acc2[1], 0, 0, 0);
        }
        float* outp = sjp + (size_t)blockIdx.x*5120;
        #pragma unroll
        for (int mi = 0; mi < 2; ++mi)
            #pragma unroll
            for (int r = 0; r < 4; ++r) {
                int b = mi*16 + pg*4 + r;
                int os = w*16 + col;
                outp[b*160 + os] = acc2[mi][r];
            }
    }
}

extern "C" void kernel_launch(void* const* d_in, const int* in_sizes, int n_in,
                              void* d_out, int out_size, void* d_ws, size_t ws_size,
                              hipStream_t stream) {
    const float* x   = (const float*)d_in[0];
    const float* c1w = (const float*)d_in[1];
    const float* c1b = (const float*)d_in[2];
    const float* pw  = (const float*)d_in[3];
    const float* pb  = (const float*)d_in[4];
    const float* Wd  = (const float*)d_in[5];
    float* out = (float*)d_out;

    // workspace map (bytes); total 69,870,656 == proven footprint
    char* wsb = (char*)d_ws;
    _Float16* ht1 = (_Float16*)(wsb);                 // 12,845,056
    _Float16* Wk1 = (_Float16*)(wsb + 12845056);      // 10,616,832
    float* Clin = (float*)(wsb + 23461888);           // 13,107,200
    char* tailb = wsb + 36569088;
    float* bij   = (float*)tailb;                     // 128,000 f -> ends 37,081,088
    float* ssq   = bij + 128000;                      // 256 f     -> ends 37,082,112
    float* vv    = ssq + 256;                         // 5,120 f   -> ends 37,102,592
    _Float16* Wh = (_Float16*)(wsb + 37102656);       // 32,768,000 B -> ends 69,870,656
    // aliases:
    float* cdenA = ssq;                      // ssq dead after k_xq2; zeroed in k_sj0_mfma
    float* cdenB = ssq + 16;
    _Float16* xq = (_Float16*)(wsb);         // 6.55MB over ht1 (dead after GEMM)
    float* sjp = (float*)(wsb + 23461888);   // over Clin (dead after xq2); 400*5120 f = 8.2MB

    hipMemsetAsync(Clin, 0, 13107200, stream);
    hipMemsetAsync(bij, 0, (128000 + 256)*sizeof(float), stream);  // bij + ssq

    k_prep_misc<<<16512, 256, 0, stream>>>(Wd, Wh, x, c1w, c1b, ht1);
    k_prep_w<<<256, 256, 0, stream>>>(pw, Wk1);
    k_prim_mfma<<<dim3(100,2,5), 512, 0, stream>>>(ht1, Wk1, Clin);
    k_ssq<<<12800, 256, 0, stream>>>(Clin, pb, ssq);
    k_xq2<<<400, 256, 0, stream>>>(Clin, pb, ssq, xq);

    // it0: uniform coupling as MFMA GEMM (also zeroes cdenA/cdenB)
    k_sj0_mfma<<<NBLK_A, 256, 0, stream>>>(Wh, xq, sjp, cdenA);
    k_reduce_squash<<<32, 640, 0, stream>>>(sjp, vv, cdenA, 0, NBLK_A, out, 0);
    // it1: fused bij-update + MFMA s~ (normalize-after-sum)
    k_fused_bs<<<400, 640, 0, stream>>>(Wh, xq, vv, bij, cdenA, sjp);
    k_reduce_squash<<<32, 640, 0, stream>>>(sjp, vv, cdenA, 1, 400, out, 0);
    // it2
    k_fused_bs<<<400, 640, 0, stream>>>(Wh, xq, vv, bij, cdenB, sjp);
    k_reduce_squash<<<32, 640, 0, stream>>>(sjp, vv, cdenB, 1, 400, out, 1);
}

// Round 24
// 494.447 us; speedup vs baseline: 1.0602x; 1.0332x over previous
//
#include <hip/hip_runtime.h>
#include <math.h>

// ---- problem constants ----
static constexpr int PDIM = 12800;      // 32ch*400
static constexpr int OSD  = 160;        // 10*16
static constexpr int NBLK_A = 200;      // it0 pass-A p-blocks (64 p each)

typedef _Float16 hv8  __attribute__((ext_vector_type(8)));
typedef _Float16 hv4  __attribute__((ext_vector_type(4)));
typedef float    f32x4 __attribute__((ext_vector_type(4)));

__device__ __forceinline__ void gload16(const void* g, void* l) {
    __builtin_amdgcn_global_load_lds(
        (const __attribute__((address_space(1))) void*)g,
        (__attribute__((address_space(3))) void*)l, 16, 0, 0);
}

// ---------------- K0: prim_w[co][ci][81] -> Wk1[k][co][ci] fp16 ----------------
__global__ void k_prep_w(const float* __restrict__ w, _Float16* __restrict__ Wk1) {
    __shared__ float s[20736];          // one co-slice: [ci=256][k=81]
    int co = blockIdx.x, t = threadIdx.x;
    const float4* src = (const float4*)(w + (size_t)co*20736);
    float4* d4 = (float4*)s;
    for (int i = t; i < 5184; i += 256) d4[i] = src[i];
    __syncthreads();
    for (int k = 0; k < 81; ++k)
        Wk1[(size_t)k*65536 + co*256 + t] = (_Float16)s[t*81 + k];
}

// ---------------- K0b+K1 merged: blocks [0,16000) Wd->fp16; [16000,16512) conv1 ----------------
__global__ void k_prep_misc(const float* __restrict__ Wd, _Float16* __restrict__ Wh,
                            const float* __restrict__ x, const float* __restrict__ w,
                            const float* __restrict__ bias, _Float16* __restrict__ ht1) {
    __shared__ float sx[1296];
    __shared__ float sw[1296];
    int tid = threadIdx.x;
    if (blockIdx.x < 16000) {
        size_t i = ((size_t)blockIdx.x*256 + tid) * 4;   // 16,384,000 floats total
        float4 v = *(const float4*)(Wd + i);
        hv4 h;
        h[0] = (_Float16)v.x; h[1] = (_Float16)v.y;
        h[2] = (_Float16)v.z; h[3] = (_Float16)v.w;
        *(hv4*)(Wh + i) = h;
        return;
    }
    int bid2 = blockIdx.x - 16000;
    int b = bid2 >> 4, cog = bid2 & 15;
    for (int i = tid; i < 1296; i += 256) {
        sx[i] = x[b*1296 + i];
        sw[i] = w[cog*1296 + i];
    }
    __syncthreads();
    for (int pos = tid; pos < 784; pos += 256) {
        int y = pos / 28, xx = pos - y*28;
        float acc[16];
        #pragma unroll
        for (int c = 0; c < 16; ++c) acc[c] = 0.f;
        for (int ky = 0; ky < 9; ++ky) {
            #pragma unroll
            for (int kx = 0; kx < 9; ++kx) {
                float xv = sx[(y+ky)*36 + xx + kx];
                #pragma unroll
                for (int c = 0; c < 16; ++c)
                    acc[c] += xv * sw[c*81 + ky*9 + kx];
            }
        }
        #pragma unroll
        for (int c = 0; c < 16; ++c) {
            float r = acc[c] + bias[cog*16 + c];
            r = r > 0.f ? r : 0.f;
            ht1[((size_t)b*784 + pos)*256 + cog*16 + c] = (_Float16)r;
        }
    }
}

// ---------------- K2: primary conv as 81 shifted GEMMs, pure fp16 MFMA ----------------
// r12 structure; ksplit=5 (r16-proven: 197us, WRITE 66MB, grid 1000 = 3.9 blk/CU).
__global__ __launch_bounds__(512, 8) void k_prim_mfma(
        const _Float16* __restrict__ ht1, const _Float16* __restrict__ Wk1,
        float* __restrict__ Clin) {
    // per-buffer (halfs): A @0 (4096), B @4096; BUF=8192 (16KB)
    __shared__ _Float16 lds[16384];
    const int t   = threadIdx.x;
    const int n0  = blockIdx.x * 128;
    const int co0 = blockIdx.y * 128;
    const int z   = blockIdx.z;
    const int klo = (z*81) / 5, khi = ((z+1)*81) / 5;
    const int NSTEP = (khi - klo) * 8;

    const int srow = t >> 2, slot = t & 3;
    const int g = slot ^ ((srow >> 1) & 3);
    const size_t aSrcOff = (size_t)(co0 + srow)*256 + g*8;
    const int n1 = n0 + srow;
    const int b1 = n1/400, rr1 = n1 - b1*400, y1 = rr1/20, x1 = rr1 - y1*20;
    const size_t bOff1 = ((size_t)b1*784 + y1*28 + x1)*256 + g*8;

    const int l = t & 63, w8 = t >> 6;
    const int wm = w8 >> 2, wn = w8 & 3;
    const int lm = l & 15, lk = l >> 4;
    int aoff[4], boff[2];
    #pragma unroll
    for (int i = 0; i < 4; ++i) {
        int ra = wm*64 + i*16 + lm;
        aoff[i] = ra*32 + ((lk ^ ((ra>>1)&3))*8);
    }
    #pragma unroll
    for (int j = 0; j < 2; ++j) {
        int rb = wn*32 + j*16 + lm;
        boff[j] = 4096 + rb*32 + ((lk ^ ((rb>>1)&3))*8);
    }

    f32x4 acc[4][2];
    #pragma unroll
    for (int i = 0; i < 4; ++i)
        #pragma unroll
        for (int j = 0; j < 2; ++j) { acc[i][j][0]=0.f; acc[i][j][1]=0.f; acc[i][j][2]=0.f; acc[i][j][3]=0.f; }

#define STAGE(S, LB) { int k_ = klo + ((S) >> 3), c_ = (S) & 7; \
        size_t ao = (size_t)k_*65536 + c_*32 + aSrcOff; \
        gload16(Wk1 + ao, (LB) + t*8); \
        int spk_ = (k_/9)*28 + (k_ - (k_/9)*9); \
        size_t so = (size_t)spk_*256 + c_*32; \
        gload16(ht1 + bOff1 + so, (LB) + 4096 + t*8); }

#define COMPUTE(L) { hv8 a1[4]; \
        _Pragma("unroll") for (int mi = 0; mi < 4; ++mi) \
            a1[mi] = *(const hv8*)((L) + aoff[mi]); \
        _Pragma("unroll") for (int nj = 0; nj < 2; ++nj) { \
            hv8 q1 = *(const hv8*)((L) + boff[nj]); \
            _Pragma("unroll") for (int mi = 0; mi < 4; ++mi) \
                acc[mi][nj] = __builtin_amdgcn_mfma_f32_16x16x32_f16(a1[mi], q1, acc[mi][nj], 0, 0, 0); } }

    STAGE(0, lds);
    __syncthreads();

    for (int s = 0; s < NSTEP; ++s) {
        const int d = s & 1;
        _Float16* Lnext = lds + (d ? 0 : 8192);
        const _Float16* L = lds + (d ? 8192 : 0);
        if ((s + 1) < NSTEP) STAGE(s+1, Lnext);
        COMPUTE(L);
        __syncthreads();
    }

    #pragma unroll
    for (int mi = 0; mi < 4; ++mi) {
        #pragma unroll
        for (int nj = 0; nj < 2; ++nj) {
            int nn = n0 + wn*32 + nj*16 + lm;
            #pragma unroll
            for (int r = 0; r < 4; ++r) {
                int co = co0 + wm*64 + mi*16 + lk*4 + r;
                atomicAdd(&Clin[(size_t)co*12800 + nn], acc[mi][nj][r]);
            }
        }
    }
#undef STAGE
#undef COMPUTE
}

// ---------------- K2b: ssq[bu] = sum over (ch,rr) of (Clin+bias)^2 — one block per (b,u) ----------------
// 256 blocks, coalesced reads (consecutive tid -> consecutive rr), direct store, no atomics.
__global__ void k_ssq(const float* __restrict__ Clin, const float* __restrict__ bias,
                      float* __restrict__ ssq) {
    __shared__ float red[256];
    int bu = blockIdx.x;                // bn = bu>>3, unit = bu&7
    int bn = bu >> 3, unit = bu & 7;
    int tid = threadIdx.x;
    float acc = 0.f;
    for (int i = tid; i < 12800; i += 256) {
        int ch = i / 400, rr = i - ch*400;
        int co = unit*32 + ch;
        float val = Clin[(size_t)co*12800 + bn*400 + rr] + bias[co];
        acc += val * val;
    }
    red[tid] = acc;
    __syncthreads();
    for (int st = 128; st > 0; st >>= 1) {
        if (tid < st) red[tid] += red[tid+st];
        __syncthreads();
    }
    if (tid == 0) ssq[bu] = red[0];
}

// ---------------- K3: xq[p][b*8+u] = fp16((Clin[co][n]+bias)*scl(b,u)) ----------------
__global__ void k_xq2(const float* __restrict__ Clin, const float* __restrict__ bias,
                      const float* __restrict__ ssq, _Float16* __restrict__ xq) {
    __shared__ float sT[32][257];
    __shared__ float sS[256];
    int p0 = blockIdx.x*32, tid = threadIdx.x;
    {
        float q = ssq[tid];
        sS[tid] = sqrtf(q) / (1.f + q);
    }
    __syncthreads();
    for (int r = 0; r < 32; ++r) {
        int e = r*256 + tid;
        int bu = e >> 5, pi = e & 31;
        int p = p0 + pi;
        int ch = p / 400, rr = p - ch*400;
        int unit = bu & 7, bn = bu >> 3;
        int co = unit*32 + ch;
        sT[pi][bu] = (Clin[(size_t)co*12800 + bn*400 + rr] + bias[co]) * sS[bu];
    }
    __syncthreads();
    for (int r = 0; r < 32; ++r)
        xq[(size_t)(p0+r)*256 + tid] = (_Float16)sT[r][tid];
}

// ---------------- K5: it0 pass A as MFMA GEMM (r18-proven) ----------------
__global__ __launch_bounds__(256) void k_sj0_mfma(const _Float16* __restrict__ Wh,
        const _Float16* __restrict__ xq, float* __restrict__ sjp,
        float* __restrict__ cdenAB) {
    __shared__ float lsj[4*5120];       // 80KB: one copy per wave
    int tid = threadIdx.x;
    if (blockIdx.x == 0 && tid < 32) cdenAB[tid] = 0.f;
    const int w = tid >> 6, l = tid & 63;
    const int col = l & 15, pg = l >> 4;
    const int p0 = blockIdx.x * 64;

    f32x4 acc[2][10];
    #pragma unroll
    for (int mi = 0; mi < 2; ++mi)
        #pragma unroll
        for (int nj = 0; nj < 10; ++nj) { acc[mi][nj][0]=0.f; acc[mi][nj][1]=0.f; acc[mi][nj][2]=0.f; acc[mi][nj][3]=0.f; }

    for (int s = 0; s < 4; ++s) {
        int pp = p0 + (w*4 + s)*4 + pg;
        hv8 a0 = *(const hv8*)(xq + (size_t)pp*256 + col*8);
        hv8 a1 = *(const hv8*)(xq + (size_t)pp*256 + (16 + col)*8);
        const hv8* wb = (const hv8*)(Wh + (size_t)pp*1280);
        #pragma unroll
        for (int nj = 0; nj < 10; ++nj) {
            hv8 bf = wb[nj*16 + col];
            acc[0][nj] = __builtin_amdgcn_mfma_f32_16x16x32_f16(a0, bf, acc[0][nj], 0, 0, 0);
            acc[1][nj] = __builtin_amdgcn_mfma_f32_16x16x32_f16(a1, bf, acc[1][nj], 0, 0, 0);
        }
    }

    float* my = lsj + w*5120;
    #pragma unroll
    for (int mi = 0; mi < 2; ++mi)
        #pragma unroll
        for (int nj = 0; nj < 10; ++nj)
            #pragma unroll
            for (int r = 0; r < 4; ++r) {
                int b = mi*16 + pg*4 + r;
                int os = nj*16 + col;
                my[b*160 + os] = acc[mi][nj][r];
            }
    __syncthreads();
    const float uc = 1.f / 12800.f;
    float* outp = sjp + (size_t)blockIdx.x*5120;
    for (int e = tid; e < 5120; e += 256)
        outp[e] = (lsj[e] + lsj[5120+e] + lsj[10240+e] + lsj[15360+e]) * uc;
}

// ---------------- K6: reduce np partials -> s_j (/cden if useDen) -> squash over O -> v ----------------
__global__ void k_reduce_squash(const float* __restrict__ sjp, float* __restrict__ v,
                                const float* __restrict__ cden, int useDen, int np,
                                float* __restrict__ dout, int writeOut) {
    __shared__ float ps[640];
    __shared__ float sc[16];
    int tid = threadIdx.x;
    int b = blockIdx.x;
    int q = tid / 160, el = tid - q*160;
    float s = 0.f;
    for (int k = q; k < np; k += 4) s += sjp[(size_t)k*5120 + b*160 + el];
    ps[tid] = s;
    __syncthreads();
    if (tid < 160) {
        float sfull = ps[tid] + ps[160+tid] + ps[320+tid] + ps[480+tid];
        if (useDen) sfull *= 1.f / cden[tid >> 4];
        ps[tid] = sfull;
    }
    __syncthreads();
    if (tid < 16) {
        float msq = 0.f;
        #pragma unroll
        for (int o = 0; o < 10; ++o) { float t_ = ps[o*16 + tid]; msq += t_*t_; }
        sc[tid] = sqrtf(msq) / (1.f + msq);
    }
    __syncthreads();
    if (tid < 160) {
        float val = ps[tid] * sc[tid & 15];
        int e = b*160 + tid;
        v[e] = val;
        if (writeOut) dout[e] = val;
    }
}

// ---------------- K7: fused pass B + next pass A; 640 thr (10 waves) — r21-proven ----------------
// phase 1: two thread-halves each cover 16 bq for thread (pl,o); LDS pair-reduce; e=exp->se.
// phase 2: wave w (of 10) owns os-tile nj=w, all 32 p (8 K-steps), disjoint sjp stores.
__global__ __launch_bounds__(640) void k_fused_bs(const _Float16* __restrict__ Wh,
        const _Float16* __restrict__ xqh, const float* __restrict__ v,
        float* __restrict__ bij, float* __restrict__ cden, float* __restrict__ sjp) {
    __shared__ float sv[5120];
    __shared__ float sxq[32*260];
    __shared__ float se[320];
    __shared__ float ph[640];
    int tid = threadIdx.x;
    int p0 = blockIdx.x*32;
    for (int e = tid; e < 5120; e += 640) sv[e] = v[e];
    for (int e = tid; e < 1024; e += 640) {
        int pl = e >> 5, grp = e & 31;
        hv8 xv = *(const hv8*)(xqh + (size_t)(p0+pl)*256 + grp*8);
        #pragma unroll
        for (int j = 0; j < 8; ++j) sxq[pl*260 + grp*8 + j] = (float)xv[j];
    }
    __syncthreads();
    // ---- phase 1: agree partials, each half covers 16 bq ----
    {
        int h = (tid >= 320) ? 1 : 0;
        int base = tid - h*320;
        int pl = base / 10, o = base - pl*10;
        int p = p0 + pl;
        const hv8* wr = (const hv8*)(Wh + (size_t)p*1280 + o*128);
        float acc = 0.f;
        int bq0 = h*16;
        #pragma unroll
        for (int hf = 0; hf < 2; ++hf) {
            hv8 wreg[8];
            #pragma unroll
            for (int i = 0; i < 8; ++i) wreg[i] = wr[hf*8 + i];
            for (int bq = bq0; bq < bq0+16; ++bq) {
                float4 x0 = *(const float4*)&sxq[pl*260 + bq*8];
                float4 x1 = *(const float4*)&sxq[pl*260 + bq*8 + 4];
                #pragma unroll
                for (int sg = 0; sg < 2; ++sg) {
                    float4 vs = *(const float4*)&sv[bq*160 + o*16 + hf*8 + sg*4];
                    float vsv[4] = {vs.x, vs.y, vs.z, vs.w};
                    #pragma unroll
                    for (int s4 = 0; s4 < 4; ++s4) {
                        hv8 wv = wreg[sg*4 + s4];
                        float uh = (float)wv[0]*x0.x + (float)wv[1]*x0.y + (float)wv[2]*x0.z + (float)wv[3]*x0.w
                                 + (float)wv[4]*x1.x + (float)wv[5]*x1.y + (float)wv[6]*x1.z + (float)wv[7]*x1.w;
                        acc += uh * vsv[s4];
                    }
                }
            }
        }
        ph[tid] = acc;
    }
    __syncthreads();
    if (tid < 320) {
        int pl = tid / 10, o = tid - pl*10;
        float acc = ph[tid] + ph[tid + 320];
        float bn_ = bij[(p0+pl)*10 + o] + acc * (1.f/32.f);
        bij[(p0+pl)*10 + o] = bn_;
        se[tid] = __expf(bn_);      // se[pl*10 + o]
    }
    __syncthreads();
    if (tid < 10) {
        float s_ = 0.f;
        #pragma unroll
        for (int j = 0; j < 32; ++j) s_ += se[tid + j*10];
        atomicAdd(&cden[tid], s_);
    }
    // ---- phase 2: wave w owns os-tile nj=w; all 32 p; direct disjoint stores ----
    {
        int w = tid >> 6, l = tid & 63;
        const int col = l & 15, pg = l >> 4;
        f32x4 acc2[2];
        acc2[0][0]=0.f; acc2[0][1]=0.f; acc2[0][2]=0.f; acc2[0][3]=0.f;
        acc2[1][0]=0.f; acc2[1][1]=0.f; acc2[1][2]=0.f; acc2[1][3]=0.f;
        for (int s2 = 0; s2 < 8; ++s2) {
            int plocal = s2*4 + pg;
            int pp = p0 + plocal;
            hv8 a0 = *(const hv8*)(xqh + (size_t)pp*256 + col*8);
            hv8 a1 = *(const hv8*)(xqh + (size_t)pp*256 + (16 + col)*8);
            const hv8* wb = (const hv8*)(Wh + (size_t)pp*1280);
            _Float16 eh = (_Float16)se[plocal*10 + w];
            hv8 bf = wb[w*16 + col];
            #pragma unroll
            for (int j = 0; j < 8; ++j) bf[j] *= eh;
            acc2[0] = __builtin_amdgcn_mfma_f32_16x16x32_f16(a0, bf, acc2[0], 0, 0, 0);
            acc2[1] = __builtin_amdgcn_mfma_f32_16x16x32_f16(a1, bf, acc2[1], 0, 0, 0);
        }
        float* outp = sjp + (size_t)blockIdx.x*5120;
        #pragma unroll
        for (int mi = 0; mi < 2; ++mi)
            #pragma unroll
            for (int r = 0; r < 4; ++r) {
                int b = mi*16 + pg*4 + r;
                int os = w*16 + col;
                outp[b*160 + os] = acc2[mi][r];
            }
    }
}

extern "C" void kernel_launch(void* const* d_in, const int* in_sizes, int n_in,
                              void* d_out, int out_size, void* d_ws, size_t ws_size,
                              hipStream_t stream) {
    const float* x   = (const float*)d_in[0];
    const float* c1w = (const float*)d_in[1];
    const float* c1b = (const float*)d_in[2];
    const float* pw  = (const float*)d_in[3];
    const float* pb  = (const float*)d_in[4];
    const float* Wd  = (const float*)d_in[5];
    float* out = (float*)d_out;

    // workspace map (bytes); total 69,870,656 == proven footprint
    char* wsb = (char*)d_ws;
    _Float16* ht1 = (_Float16*)(wsb);                 // 12,845,056
    _Float16* Wk1 = (_Float16*)(wsb + 12845056);      // 10,616,832
    float* Clin = (float*)(wsb + 23461888);           // 13,107,200
    char* tailb = wsb + 36569088;
    float* bij   = (float*)tailb;                     // 128,000 f -> ends 37,081,088
    float* ssq   = bij + 128000;                      // 256 f     -> ends 37,082,112
    float* vv    = ssq + 256;                         // 5,120 f   -> ends 37,102,592
    _Float16* Wh = (_Float16*)(wsb + 37102656);       // 32,768,000 B -> ends 69,870,656
    // aliases:
    float* cdenA = ssq;                      // ssq dead after k_xq2; zeroed in k_sj0_mfma
    float* cdenB = ssq + 16;
    _Float16* xq = (_Float16*)(wsb);         // 6.55MB over ht1 (dead after GEMM)
    float* sjp = (float*)(wsb + 23461888);   // over Clin (dead after xq2); 400*5120 f = 8.2MB

    hipMemsetAsync(Clin, 0, 13107200, stream);
    hipMemsetAsync(bij, 0, 128000*sizeof(float), stream);   // bij only (ssq direct-stored now)

    k_prep_misc<<<16512, 256, 0, stream>>>(Wd, Wh, x, c1w, c1b, ht1);
    k_prep_w<<<256, 256, 0, stream>>>(pw, Wk1);
    k_prim_mfma<<<dim3(100,2,5), 512, 0, stream>>>(ht1, Wk1, Clin);
    k_ssq<<<256, 256, 0, stream>>>(Clin, pb, ssq);
    k_xq2<<<400, 256, 0, stream>>>(Clin, pb, ssq, xq);

    // it0: uniform coupling as MFMA GEMM (also zeroes cdenA/cdenB)
    k_sj0_mfma<<<NBLK_A, 256, 0, stream>>>(Wh, xq, sjp, cdenA);
    k_reduce_squash<<<32, 640, 0, stream>>>(sjp, vv, cdenA, 0, NBLK_A, out, 0);
    // it1: fused bij-update + MFMA s~ (normalize-after-sum)
    k_fused_bs<<<400, 640, 0, stream>>>(Wh, xq, vv, bij, cdenA, sjp);
    k_reduce_squash<<<32, 640, 0, stream>>>(sjp, vv, cdenA, 1, 400, out, 0);
    // it2
    k_fused_bs<<<400, 640, 0, stream>>>(Wh, xq, vv, bij, cdenB, sjp);
    k_reduce_squash<<<32, 640, 0, stream>>>(sjp, vv, cdenB, 1, 400, out, 1);
}

// Round 25
// 493.592 us; speedup vs baseline: 1.0620x; 1.0017x over previous
//
#include <hip/hip_runtime.h>
#include <math.h>

// ---- problem constants ----
static constexpr int PDIM = 12800;      // 32ch*400
static constexpr int OSD  = 160;        // 10*16
static constexpr int NBLK_A = 200;      // it0 pass-A p-blocks (64 p each)

typedef _Float16 hv8  __attribute__((ext_vector_type(8)));
typedef _Float16 hv4  __attribute__((ext_vector_type(4)));
typedef float    f32x4 __attribute__((ext_vector_type(4)));

__device__ __forceinline__ void gload16(const void* g, void* l) {
    __builtin_amdgcn_global_load_lds(
        (const __attribute__((address_space(1))) void*)g,
        (__attribute__((address_space(3))) void*)l, 16, 0, 0);
}

// ---------------- K0: prim_w[co][ci][81] -> Wk1[k][co][ci] fp16 ----------------
__global__ void k_prep_w(const float* __restrict__ w, _Float16* __restrict__ Wk1) {
    __shared__ float s[20736];          // one co-slice: [ci=256][k=81]
    int co = blockIdx.x, t = threadIdx.x;
    const float4* src = (const float4*)(w + (size_t)co*20736);
    float4* d4 = (float4*)s;
    for (int i = t; i < 5184; i += 256) d4[i] = src[i];
    __syncthreads();
    for (int k = 0; k < 81; ++k)
        Wk1[(size_t)k*65536 + co*256 + t] = (_Float16)s[t*81 + k];
}

// ---------------- K0b+K1 merged: blocks [0,16000) Wd->fp16; [16000,16512) conv1 ----------------
__global__ void k_prep_misc(const float* __restrict__ Wd, _Float16* __restrict__ Wh,
                            const float* __restrict__ x, const float* __restrict__ w,
                            const float* __restrict__ bias, _Float16* __restrict__ ht1) {
    __shared__ float sx[1296];
    __shared__ float sw[1296];
    int tid = threadIdx.x;
    if (blockIdx.x < 16000) {
        size_t i = ((size_t)blockIdx.x*256 + tid) * 4;   // 16,384,000 floats total
        float4 v = *(const float4*)(Wd + i);
        hv4 h;
        h[0] = (_Float16)v.x; h[1] = (_Float16)v.y;
        h[2] = (_Float16)v.z; h[3] = (_Float16)v.w;
        *(hv4*)(Wh + i) = h;
        return;
    }
    int bid2 = blockIdx.x - 16000;
    int b = bid2 >> 4, cog = bid2 & 15;
    for (int i = tid; i < 1296; i += 256) {
        sx[i] = x[b*1296 + i];
        sw[i] = w[cog*1296 + i];
    }
    __syncthreads();
    for (int pos = tid; pos < 784; pos += 256) {
        int y = pos / 28, xx = pos - y*28;
        float acc[16];
        #pragma unroll
        for (int c = 0; c < 16; ++c) acc[c] = 0.f;
        for (int ky = 0; ky < 9; ++ky) {
            #pragma unroll
            for (int kx = 0; kx < 9; ++kx) {
                float xv = sx[(y+ky)*36 + xx + kx];
                #pragma unroll
                for (int c = 0; c < 16; ++c)
                    acc[c] += xv * sw[c*81 + ky*9 + kx];
            }
        }
        #pragma unroll
        for (int c = 0; c < 16; ++c) {
            float r = acc[c] + bias[cog*16 + c];
            r = r > 0.f ? r : 0.f;
            ht1[((size_t)b*784 + pos)*256 + cog*16 + c] = (_Float16)r;
        }
    }
}

// ---------------- K2: primary conv as 81 shifted GEMMs, pure fp16 MFMA ----------------
// r12 structure; ksplit=5 (r16-proven: 197us, WRITE 66MB, grid 1000 = 3.9 blk/CU).
__global__ __launch_bounds__(512, 8) void k_prim_mfma(
        const _Float16* __restrict__ ht1, const _Float16* __restrict__ Wk1,
        float* __restrict__ Clin) {
    // per-buffer (halfs): A @0 (4096), B @4096; BUF=8192 (16KB)
    __shared__ _Float16 lds[16384];
    const int t   = threadIdx.x;
    const int n0  = blockIdx.x * 128;
    const int co0 = blockIdx.y * 128;
    const int z   = blockIdx.z;
    const int klo = (z*81) / 5, khi = ((z+1)*81) / 5;
    const int NSTEP = (khi - klo) * 8;

    const int srow = t >> 2, slot = t & 3;
    const int g = slot ^ ((srow >> 1) & 3);
    const size_t aSrcOff = (size_t)(co0 + srow)*256 + g*8;
    const int n1 = n0 + srow;
    const int b1 = n1/400, rr1 = n1 - b1*400, y1 = rr1/20, x1 = rr1 - y1*20;
    const size_t bOff1 = ((size_t)b1*784 + y1*28 + x1)*256 + g*8;

    const int l = t & 63, w8 = t >> 6;
    const int wm = w8 >> 2, wn = w8 & 3;
    const int lm = l & 15, lk = l >> 4;
    int aoff[4], boff[2];
    #pragma unroll
    for (int i = 0; i < 4; ++i) {
        int ra = wm*64 + i*16 + lm;
        aoff[i] = ra*32 + ((lk ^ ((ra>>1)&3))*8);
    }
    #pragma unroll
    for (int j = 0; j < 2; ++j) {
        int rb = wn*32 + j*16 + lm;
        boff[j] = 4096 + rb*32 + ((lk ^ ((rb>>1)&3))*8);
    }

    f32x4 acc[4][2];
    #pragma unroll
    for (int i = 0; i < 4; ++i)
        #pragma unroll
        for (int j = 0; j < 2; ++j) { acc[i][j][0]=0.f; acc[i][j][1]=0.f; acc[i][j][2]=0.f; acc[i][j][3]=0.f; }

#define STAGE(S, LB) { int k_ = klo + ((S) >> 3), c_ = (S) & 7; \
        size_t ao = (size_t)k_*65536 + c_*32 + aSrcOff; \
        gload16(Wk1 + ao, (LB) + t*8); \
        int spk_ = (k_/9)*28 + (k_ - (k_/9)*9); \
        size_t so = (size_t)spk_*256 + c_*32; \
        gload16(ht1 + bOff1 + so, (LB) + 4096 + t*8); }

#define COMPUTE(L) { hv8 a1[4]; \
        _Pragma("unroll") for (int mi = 0; mi < 4; ++mi) \
            a1[mi] = *(const hv8*)((L) + aoff[mi]); \
        _Pragma("unroll") for (int nj = 0; nj < 2; ++nj) { \
            hv8 q1 = *(const hv8*)((L) + boff[nj]); \
            _Pragma("unroll") for (int mi = 0; mi < 4; ++mi) \
                acc[mi][nj] = __builtin_amdgcn_mfma_f32_16x16x32_f16(a1[mi], q1, acc[mi][nj], 0, 0, 0); } }

    STAGE(0, lds);
    __syncthreads();

    for (int s = 0; s < NSTEP; ++s) {
        const int d = s & 1;
        _Float16* Lnext = lds + (d ? 0 : 8192);
        const _Float16* L = lds + (d ? 8192 : 0);
        if ((s + 1) < NSTEP) STAGE(s+1, Lnext);
        COMPUTE(L);
        __syncthreads();
    }

    #pragma unroll
    for (int mi = 0; mi < 4; ++mi) {
        #pragma unroll
        for (int nj = 0; nj < 2; ++nj) {
            int nn = n0 + wn*32 + nj*16 + lm;
            #pragma unroll
            for (int r = 0; r < 4; ++r) {
                int co = co0 + wm*64 + mi*16 + lk*4 + r;
                atomicAdd(&Clin[(size_t)co*12800 + nn], acc[mi][nj][r]);
            }
        }
    }
#undef STAGE
#undef COMPUTE
}

// ---------------- K2b: ssq[bu] = sum over (ch,rr) of (Clin+bias)^2 — one block per (b,u) ----------------
__global__ void k_ssq(const float* __restrict__ Clin, const float* __restrict__ bias,
                      float* __restrict__ ssq) {
    __shared__ float red[256];
    int bu = blockIdx.x;
    int bn = bu >> 3, unit = bu & 7;
    int tid = threadIdx.x;
    float acc = 0.f;
    for (int i = tid; i < 12800; i += 256) {
        int ch = i / 400, rr = i - ch*400;
        int co = unit*32 + ch;
        float val = Clin[(size_t)co*12800 + bn*400 + rr] + bias[co];
        acc += val * val;
    }
    red[tid] = acc;
    __syncthreads();
    for (int st = 128; st > 0; st >>= 1) {
        if (tid < st) red[tid] += red[tid+st];
        __syncthreads();
    }
    if (tid == 0) ssq[bu] = red[0];
}

// ---------------- K3: xq[p][b*8+u] = fp16((Clin[co][n]+bias)*scl(b,u)) ----------------
__global__ void k_xq2(const float* __restrict__ Clin, const float* __restrict__ bias,
                      const float* __restrict__ ssq, _Float16* __restrict__ xq) {
    __shared__ float sT[32][257];
    __shared__ float sS[256];
    int p0 = blockIdx.x*32, tid = threadIdx.x;
    {
        float q = ssq[tid];
        sS[tid] = sqrtf(q) / (1.f + q);
    }
    __syncthreads();
    for (int r = 0; r < 32; ++r) {
        int e = r*256 + tid;
        int bu = e >> 5, pi = e & 31;
        int p = p0 + pi;
        int ch = p / 400, rr = p - ch*400;
        int unit = bu & 7, bn = bu >> 3;
        int co = unit*32 + ch;
        sT[pi][bu] = (Clin[(size_t)co*12800 + bn*400 + rr] + bias[co]) * sS[bu];
    }
    __syncthreads();
    for (int r = 0; r < 32; ++r)
        xq[(size_t)(p0+r)*256 + tid] = (_Float16)sT[r][tid];
}

// ---------------- K5: it0 pass A as MFMA GEMM (r18-proven) ----------------
__global__ __launch_bounds__(256) void k_sj0_mfma(const _Float16* __restrict__ Wh,
        const _Float16* __restrict__ xq, float* __restrict__ sjp,
        float* __restrict__ cdenAB) {
    __shared__ float lsj[4*5120];       // 80KB: one copy per wave
    int tid = threadIdx.x;
    if (blockIdx.x == 0 && tid < 32) cdenAB[tid] = 0.f;
    const int w = tid >> 6, l = tid & 63;
    const int col = l & 15, pg = l >> 4;
    const int p0 = blockIdx.x * 64;

    f32x4 acc[2][10];
    #pragma unroll
    for (int mi = 0; mi < 2; ++mi)
        #pragma unroll
        for (int nj = 0; nj < 10; ++nj) { acc[mi][nj][0]=0.f; acc[mi][nj][1]=0.f; acc[mi][nj][2]=0.f; acc[mi][nj][3]=0.f; }

    for (int s = 0; s < 4; ++s) {
        int pp = p0 + (w*4 + s)*4 + pg;
        hv8 a0 = *(const hv8*)(xq + (size_t)pp*256 + col*8);
        hv8 a1 = *(const hv8*)(xq + (size_t)pp*256 + (16 + col)*8);
        const hv8* wb = (const hv8*)(Wh + (size_t)pp*1280);
        #pragma unroll
        for (int nj = 0; nj < 10; ++nj) {
            hv8 bf = wb[nj*16 + col];
            acc[0][nj] = __builtin_amdgcn_mfma_f32_16x16x32_f16(a0, bf, acc[0][nj], 0, 0, 0);
            acc[1][nj] = __builtin_amdgcn_mfma_f32_16x16x32_f16(a1, bf, acc[1][nj], 0, 0, 0);
        }
    }

    float* my = lsj + w*5120;
    #pragma unroll
    for (int mi = 0; mi < 2; ++mi)
        #pragma unroll
        for (int nj = 0; nj < 10; ++nj)
            #pragma unroll
            for (int r = 0; r < 4; ++r) {
                int b = mi*16 + pg*4 + r;
                int os = nj*16 + col;
                my[b*160 + os] = acc[mi][nj][r];
            }
    __syncthreads();
    const float uc = 1.f / 12800.f;
    float* outp = sjp + (size_t)blockIdx.x*5120;
    for (int e = tid; e < 5120; e += 256)
        outp[e] = (lsj[e] + lsj[5120+e] + lsj[10240+e] + lsj[15360+e]) * uc;
}

// ---------------- K6: reduce np partials -> s_j (/cden if useDen) -> squash over O -> v ----------------
__global__ void k_reduce_squash(const float* __restrict__ sjp, float* __restrict__ v,
                                const float* __restrict__ cden, int useDen, int np,
                                float* __restrict__ dout, int writeOut) {
    __shared__ float ps[640];
    __shared__ float sc[16];
    int tid = threadIdx.x;
    int b = blockIdx.x;
    int q = tid / 160, el = tid - q*160;
    float s = 0.f;
    for (int k = q; k < np; k += 4) s += sjp[(size_t)k*5120 + b*160 + el];
    ps[tid] = s;
    __syncthreads();
    if (tid < 160) {
        float sfull = ps[tid] + ps[160+tid] + ps[320+tid] + ps[480+tid];
        if (useDen) sfull *= 1.f / cden[tid >> 4];
        ps[tid] = sfull;
    }
    __syncthreads();
    if (tid < 16) {
        float msq = 0.f;
        #pragma unroll
        for (int o = 0; o < 10; ++o) { float t_ = ps[o*16 + tid]; msq += t_*t_; }
        sc[tid] = sqrtf(msq) / (1.f + msq);
    }
    __syncthreads();
    if (tid < 160) {
        float val = ps[tid] * sc[tid & 15];
        int e = b*160 + tid;
        v[e] = val;
        if (writeOut) dout[e] = val;
    }
}

// ---------------- K7: fused pass B + next pass A; 640 thr; sv2 padded [o][b][s] ----------------
// phase 1: two thread-halves each cover 16 bq for thread (pl,o); LDS pair-reduce; e=exp->se.
// sv2[o*516 + b*16 + s]: o-stride 516 f -> banks 4 apart (<=2-way, free) vs 5-way unpadded.
// phase 2: wave w (of 10) owns os-tile nj=w, all 32 p (8 K-steps), disjoint sjp stores.
__global__ __launch_bounds__(640) void k_fused_bs(const _Float16* __restrict__ Wh,
        const _Float16* __restrict__ xqh, const float* __restrict__ v,
        float* __restrict__ bij, float* __restrict__ cden, float* __restrict__ sjp) {
    __shared__ float sv2[10*516];       // 20,640B padded [o][b][s]
    __shared__ float sxq[32*260];
    __shared__ float se[320];
    __shared__ float ph[640];
    int tid = threadIdx.x;
    int p0 = blockIdx.x*32;
    for (int e = tid; e < 5120; e += 640) {
        int b = e / 160, rem = e - b*160;
        int o = rem >> 4, s = rem & 15;
        sv2[o*516 + b*16 + s] = v[e];
    }
    for (int e = tid; e < 1024; e += 640) {
        int pl = e >> 5, grp = e & 31;
        hv8 xv = *(const hv8*)(xqh + (size_t)(p0+pl)*256 + grp*8);
        #pragma unroll
        for (int j = 0; j < 8; ++j) sxq[pl*260 + grp*8 + j] = (float)xv[j];
    }
    __syncthreads();
    // ---- phase 1: agree partials, each half covers 16 bq ----
    {
        int h = (tid >= 320) ? 1 : 0;
        int base = tid - h*320;
        int pl = base / 10, o = base - pl*10;
        int p = p0 + pl;
        const hv8* wr = (const hv8*)(Wh + (size_t)p*1280 + o*128);
        float acc = 0.f;
        int bq0 = h*16;
        #pragma unroll
        for (int hf = 0; hf < 2; ++hf) {
            hv8 wreg[8];
            #pragma unroll
            for (int i = 0; i < 8; ++i) wreg[i] = wr[hf*8 + i];
            for (int bq = bq0; bq < bq0+16; ++bq) {
                float4 x0 = *(const float4*)&sxq[pl*260 + bq*8];
                float4 x1 = *(const float4*)&sxq[pl*260 + bq*8 + 4];
                #pragma unroll
                for (int sg = 0; sg < 2; ++sg) {
                    float4 vs = *(const float4*)&sv2[o*516 + bq*16 + hf*8 + sg*4];
                    float vsv[4] = {vs.x, vs.y, vs.z, vs.w};
                    #pragma unroll
                    for (int s4 = 0; s4 < 4; ++s4) {
                        hv8 wv = wreg[sg*4 + s4];
                        float uh = (float)wv[0]*x0.x + (float)wv[1]*x0.y + (float)wv[2]*x0.z + (float)wv[3]*x0.w
                                 + (float)wv[4]*x1.x + (float)wv[5]*x1.y + (float)wv[6]*x1.z + (float)wv[7]*x1.w;
                        acc += uh * vsv[s4];
                    }
                }
            }
        }
        ph[tid] = acc;
    }
    __syncthreads();
    if (tid < 320) {
        int pl = tid / 10, o = tid - pl*10;
        float acc = ph[tid] + ph[tid + 320];
        float bn_ = bij[(p0+pl)*10 + o] + acc * (1.f/32.f);
        bij[(p0+pl)*10 + o] = bn_;
        se[tid] = __expf(bn_);      // se[pl*10 + o]
    }
    __syncthreads();
    if (tid < 10) {
        float s_ = 0.f;
        #pragma unroll
        for (int j = 0; j < 32; ++j) s_ += se[tid + j*10];
        atomicAdd(&cden[tid], s_);
    }
    // ---- phase 2: wave w owns os-tile nj=w; all 32 p; direct disjoint stores ----
    {
        int w = tid >> 6, l = tid & 63;
        const int col = l & 15, pg = l >> 4;
        f32x4 acc2[2];
        acc2[0][0]=0.f; acc2[0][1]=0.f; acc2[0][2]=0.f; acc2[0][3]=0.f;
        acc2[1][0]=0.f; acc2[1][1]=0.f; acc2[1][2]=0.f; acc2[1][3]=0.f;
        for (int s2 = 0; s2 < 8; ++s2) {
            int plocal = s2*4 + pg;
            int pp = p0 + plocal;
            hv8 a0 = *(const hv8*)(xqh + (size_t)pp*256 + col*8);
            hv8 a1 = *(const hv8*)(xqh + (size_t)pp*256 + (16 + col)*8);
            const hv8* wb = (const hv8*)(Wh + (size_t)pp*1280);
            _Float16 eh = (_Float16)se[plocal*10 + w];
            hv8 bf = wb[w*16 + col];
            #pragma unroll
            for (int j = 0; j < 8; ++j) bf[j] *= eh;
            acc2[0] = __builtin_amdgcn_mfma_f32_16x16x32_f16(a0, bf, acc2[0], 0, 0, 0);
            acc2[1] = __builtin_amdgcn_mfma_f32_16x16x32_f16(a1, bf, acc2[1], 0, 0, 0);
        }
        float* outp = sjp + (size_t)blockIdx.x*5120;
        #pragma unroll
        for (int mi = 0; mi < 2; ++mi)
            #pragma unroll
            for (int r = 0; r < 4; ++r) {
                int b = mi*16 + pg*4 + r;
                int os = w*16 + col;
                outp[b*160 + os] = acc2[mi][r];
            }
    }
}

extern "C" void kernel_launch(void* const* d_in, const int* in_sizes, int n_in,
                              void* d_out, int out_size, void* d_ws, size_t ws_size,
                              hipStream_t stream) {
    const float* x   = (const float*)d_in[0];
    const float* c1w = (const float*)d_in[1];
    const float* c1b = (const float*)d_in[2];
    const float* pw  = (const float*)d_in[3];
    const float* pb  = (const float*)d_in[4];
    const float* Wd  = (const float*)d_in[5];
    float* out = (float*)d_out;

    // workspace map (bytes); total 69,870,656 == proven footprint
    char* wsb = (char*)d_ws;
    _Float16* ht1 = (_Float16*)(wsb);                 // 12,845,056
    _Float16* Wk1 = (_Float16*)(wsb + 12845056);      // 10,616,832
    float* Clin = (float*)(wsb + 23461888);           // 13,107,200
    char* tailb = wsb + 36569088;
    float* bij   = (float*)tailb;                     // 128,000 f -> ends 37,081,088
    float* ssq   = bij + 128000;                      // 256 f     -> ends 37,082,112
    float* vv    = ssq + 256;                         // 5,120 f   -> ends 37,102,592
    _Float16* Wh = (_Float16*)(wsb + 37102656);       // 32,768,000 B -> ends 69,870,656
    // aliases:
    float* cdenA = ssq;                      // ssq dead after k_xq2; zeroed in k_sj0_mfma
    float* cdenB = ssq + 16;
    _Float16* xq = (_Float16*)(wsb);         // 6.55MB over ht1 (dead after GEMM)
    float* sjp = (float*)(wsb + 23461888);   // over Clin (dead after xq2); 400*5120 f = 8.2MB

    hipMemsetAsync(Clin, 0, 13107200, stream);
    hipMemsetAsync(bij, 0, 128000*sizeof(float), stream);   // bij only (ssq direct-stored)

    k_prep_misc<<<16512, 256, 0, stream>>>(Wd, Wh, x, c1w, c1b, ht1);
    k_prep_w<<<256, 256, 0, stream>>>(pw, Wk1);
    k_prim_mfma<<<dim3(100,2,5), 512, 0, stream>>>(ht1, Wk1, Clin);
    k_ssq<<<256, 256, 0, stream>>>(Clin, pb, ssq);
    k_xq2<<<400, 256, 0, stream>>>(Clin, pb, ssq, xq);

    // it0: uniform coupling as MFMA GEMM (also zeroes cdenA/cdenB)
    k_sj0_mfma<<<NBLK_A, 256, 0, stream>>>(Wh, xq, sjp, cdenA);
    k_reduce_squash<<<32, 640, 0, stream>>>(sjp, vv, cdenA, 0, NBLK_A, out, 0);
    // it1: fused bij-update + MFMA s~ (normalize-after-sum)
    k_fused_bs<<<400, 640, 0, stream>>>(Wh, xq, vv, bij, cdenA, sjp);
    k_reduce_squash<<<32, 640, 0, stream>>>(sjp, vv, cdenA, 1, 400, out, 0);
    // it2
    k_fused_bs<<<400, 640, 0, stream>>>(Wh, xq, vv, bij, cdenB, sjp);
    k_reduce_squash<<<32, 640, 0, stream>>>(sjp, vv, cdenB, 1, 400, out, 1);
}